// Round 5
// baseline (8513.437 us; speedup 1.0000x reference)
//
#include <hip/hip_runtime.h>
#include <hip/hip_bf16.h>

#define SEQ 512
#define NB  64
#define HF  1024

typedef float f32x4 __attribute__((ext_vector_type(4)));
typedef short s16x8 __attribute__((ext_vector_type(8)));
typedef short s16x4 __attribute__((ext_vector_type(4)));
typedef _Float16 f16x8 __attribute__((ext_vector_type(8)));
typedef unsigned long long u64;
typedef u64 u64x2 __attribute__((ext_vector_type(2)));

__device__ __forceinline__ unsigned short bf16_rne(float f) {
    unsigned u = __builtin_bit_cast(unsigned, f);
    u += 0x7FFFu + ((u >> 16) & 1u);
    return (unsigned short)(u >> 16);
}

// split f = hi + lo (hi = truncated bf16, lo = rne bf16 of exact remainder)
__device__ __forceinline__ void bf16_split(float f, short& hi, short& lo) {
    unsigned u = __builtin_bit_cast(unsigned, f);
    hi = (short)(u >> 16);
    float fh = __builtin_bit_cast(float, u & 0xFFFF0000u);
    lo = (short)bf16_rne(f - fh);
}

__device__ __forceinline__ f32x4 mfma16(s16x8 a, s16x8 b, f32x4 c) {
    return __builtin_amdgcn_mfma_f32_16x16x32_bf16(a, b, c, 0, 0, 0);
}

__device__ __forceinline__ f32x4 mfma16f(f16x8 a, f16x8 b, f32x4 c) {
    return __builtin_amdgcn_mfma_f32_16x16x32_f16(a, b, c, 0, 0, 0);
}

__device__ __forceinline__ u64 ald(const u64* p) {
    return __hip_atomic_load(p, __ATOMIC_RELAXED, __HIP_MEMORY_SCOPE_AGENT);
}

// ---------------------------------------------------------------------------
// Phase 1: Ux = X @ U^T + U_b   (written into d_out, layout [B,S,H] = [32768,1024])
// 128x128 tiles, K-step 32, split-bf16 (3-term) MFMA.  (unchanged — passed R2-R4)
// ---------------------------------------------------------------------------
__global__ __launch_bounds__(256, 2) void ux_gemm(const float* __restrict__ X,
                                                  const float* __restrict__ U,
                                                  const float* __restrict__ Ubias,
                                                  float* __restrict__ out) {
    __shared__ short Ah[128][40], Al[128][40], Bh[128][40], Bl[128][40];

    int bid = blockIdx.x;                    // 2048 = 256 m-tiles * 8 n-tiles
    int swz = (bid & 7) * 256 + (bid >> 3);  // XCD-contiguous chunks (2048 % 8 == 0)
    int tm = swz & 255;
    int tn = swz >> 8;

    int tid  = threadIdx.x;
    int lrow = tid >> 3;           // 0..31
    int lcol = (tid & 7) << 2;     // 0,4,..,28

    int wave = tid >> 6, lane = tid & 63;
    int wr = (wave >> 1) << 6;     // wave row offset (0/64)
    int wc = (wave & 1) << 6;      // wave col offset (0/64)
    int fr = lane & 15, fkq = lane >> 4;

    const float* Xb = X + (size_t)tm * 128 * HF;
    const float* Ub = U + (size_t)tn * 128 * HF;

    f32x4 acc[4][4];
    #pragma unroll
    for (int mi = 0; mi < 4; ++mi)
        #pragma unroll
        for (int ni = 0; ni < 4; ++ni)
            acc[mi][ni] = f32x4{0.f, 0.f, 0.f, 0.f};

    for (int kt = 0; kt < HF; kt += 32) {
        __syncthreads();
        #pragma unroll
        for (int p = 0; p < 4; ++p) {
            int r = lrow + (p << 5);
            f32x4 xv = *(const f32x4*)(Xb + (size_t)r * HF + kt + lcol);
            f32x4 uv = *(const f32x4*)(Ub + (size_t)r * HF + kt + lcol);
            s16x4 xh, xl, uh, ul;
            #pragma unroll
            for (int e = 0; e < 4; ++e) {
                short h_, l_;
                bf16_split(xv[e], h_, l_); xh[e] = h_; xl[e] = l_;
                bf16_split(uv[e], h_, l_); uh[e] = h_; ul[e] = l_;
            }
            *(s16x4*)&Ah[r][lcol] = xh;
            *(s16x4*)&Al[r][lcol] = xl;
            *(s16x4*)&Bh[r][lcol] = uh;
            *(s16x4*)&Bl[r][lcol] = ul;
        }
        __syncthreads();

        s16x8 afh[4], afl[4], bfh[4], bfl[4];
        #pragma unroll
        for (int mi = 0; mi < 4; ++mi) {
            afh[mi] = *(const s16x8*)&Ah[wr + mi * 16 + fr][fkq * 8];
            afl[mi] = *(const s16x8*)&Al[wr + mi * 16 + fr][fkq * 8];
            bfh[mi] = *(const s16x8*)&Bh[wc + mi * 16 + fr][fkq * 8];
            bfl[mi] = *(const s16x8*)&Bl[wc + mi * 16 + fr][fkq * 8];
        }
        #pragma unroll
        for (int mi = 0; mi < 4; ++mi)
            #pragma unroll
            for (int ni = 0; ni < 4; ++ni)
                acc[mi][ni] = mfma16(afh[mi], bfh[ni], acc[mi][ni]);
        #pragma unroll
        for (int mi = 0; mi < 4; ++mi)
            #pragma unroll
            for (int ni = 0; ni < 4; ++ni)
                acc[mi][ni] = mfma16(afh[mi], bfl[ni], acc[mi][ni]);
        #pragma unroll
        for (int mi = 0; mi < 4; ++mi)
            #pragma unroll
            for (int ni = 0; ni < 4; ++ni)
                acc[mi][ni] = mfma16(afl[mi], bfh[ni], acc[mi][ni]);
    }

    // epilogue: C/D layout col = lane&15, row = (lane>>4)*4 + i  [m89]
    #pragma unroll
    for (int ni = 0; ni < 4; ++ni) {
        int col = tn * 128 + wc + ni * 16 + fr;
        float ub = Ubias[col];
        #pragma unroll
        for (int mi = 0; mi < 4; ++mi) {
            #pragma unroll
            for (int i = 0; i < 4; ++i) {
                int row = tm * 128 + wr + mi * 16 + fkq * 4 + i;
                out[(size_t)row * HF + col] = acc[mi][ni][i] + ub;
            }
        }
    }
}

// ---------------------------------------------------------------------------
// Phase 2: 512 sequential steps  h = tanh(Ux_t + h@W^T + W_b)
// v5: 32 WGs = 4 groups x 8 WGs (512 thr = 8 waves x 16 cols), W f16 resident.
//   - NO LDS: MFMA A-frags loaded DIRECTLY LLC->VGPR (u64-pair relaxed agent
//     atomics, 2-deep 8-kt block software pipeline). Per-lane addr == frag
//     layout, so the load IS the fragment.
//   - h stored linearly (no swizzle needed anymore).
//   - out stores + next-step Ux loads issued AFTER flag publish (off the
//     critical path); vmcnt(0) drain covers only the 4 h stores.
// ---------------------------------------------------------------------------
__global__ __launch_bounds__(512, 2) void rnn_scan(const float* __restrict__ Ww,
                                                   const float* __restrict__ Wb,
                                                   float* __restrict__ out,
                                                   _Float16* __restrict__ hb,
                                                   unsigned int* __restrict__ flags) {
    int bid   = blockIdx.x;        // 32
    int btile = bid >> 3;          // 0..3  (16 batches each)
    int wgidx = bid & 7;           // slot in sync group
    int tid   = threadIdx.x;       // 0..511
    int wave  = tid >> 6, lane = tid & 63;
    int fr    = lane & 15, fkq = lane >> 4;
    int j     = ((wgidx * 8 + wave) << 4) + fr;   // this lane's output column
    int b0    = btile << 4;

    // --- prologue: W row j as single f16 frags (128 regs, AGPR-resident) ---
    f16x8 wf[32];
    {
        const float* wp = Ww + (size_t)j * HF + fkq * 8;
        #pragma unroll
        for (int kt = 0; kt < 32; ++kt) {
            f32x4 a = *(const f32x4*)(wp + kt * 32);
            f32x4 b = *(const f32x4*)(wp + kt * 32 + 4);
            f16x8 w;
            #pragma unroll
            for (int e = 0; e < 4; ++e) {
                w[e]     = (_Float16)a[e];
                w[e + 4] = (_Float16)b[e];
            }
            wf[kt] = w;
        }
    }
    float wb = Wb[j];

    unsigned int* grp_flags = flags + btile * 16;

    // ux for t=0
    float ux[4];
    #pragma unroll
    for (int i = 0; i < 4; ++i) {
        int r = b0 + fkq * 4 + i;
        ux[i] = out[((size_t)r * SEQ + 0) * HF + j];
    }

    #pragma unroll 1
    for (int t = 0; t < SEQ; ++t) {
        f32x4 sum = {0.f, 0.f, 0.f, 0.f};
        if (t > 0) {
            // wait for all 8 WGs of this group to finish step t-1
            unsigned int v;
            do {
                v = (lane < 8)
                    ? __hip_atomic_load(&grp_flags[lane], __ATOMIC_RELAXED,
                                        __HIP_MEMORY_SCOPE_AGENT)
                    : 0xFFFFFFFFu;
            } while (!__all(v >= (unsigned int)t));

            // direct LLC->reg A-fragments: lane (fr,fkq) reads
            // hb[b0+fr][fkq*8 + kt*32 .. +8] — 2-deep 8-kt pipeline
            int par = (t - 1) & 1;
            const u64* lanep =
                (const u64*)(hb + ((size_t)par * NB + b0 + fr) * HF + fkq * 8);
            u64 bA[2][8], bB[2][8];
            #pragma unroll
            for (int q = 0; q < 8; ++q) {
                bA[0][q] = ald(lanep + q * 8);
                bB[0][q] = ald(lanep + q * 8 + 1);
            }
            f32x4 a0 = {0.f,0.f,0.f,0.f}, a1 = a0, a2 = a0, a3 = a0;
            #pragma unroll
            for (int blk = 0; blk < 4; ++blk) {
                if (blk < 3) {
                    #pragma unroll
                    for (int q = 0; q < 8; ++q) {
                        bA[(blk + 1) & 1][q] = ald(lanep + (blk + 1) * 64 + q * 8);
                        bB[(blk + 1) & 1][q] = ald(lanep + (blk + 1) * 64 + q * 8 + 1);
                    }
                }
                #pragma unroll
                for (int q = 0; q < 8; ++q) {
                    u64x2 pr;
                    pr[0] = bA[blk & 1][q];
                    pr[1] = bB[blk & 1][q];
                    f16x8 hv = __builtin_bit_cast(f16x8, pr);
                    int kt = blk * 8 + q;
                    if ((q & 3) == 0)      a0 = mfma16f(hv, wf[kt], a0);
                    else if ((q & 3) == 1) a1 = mfma16f(hv, wf[kt], a1);
                    else if ((q & 3) == 2) a2 = mfma16f(hv, wf[kt], a2);
                    else                   a3 = mfma16f(hv, wf[kt], a3);
                }
            }
            sum = (a0 + a1) + (a2 + a3);
        }

        // --- compute h; store ONLY h (linear, sc1 -> LLC) before the flag ---
        float hv4[4];
        int par_w = t & 1;
        #pragma unroll
        for (int i = 0; i < 4; ++i) {
            int r = b0 + fkq * 4 + i;
            float p = ux[i] + sum[i] + wb;
            p = fminf(fmaxf(p, -12.f), 12.f);
            float e2 = __expf(2.f * p);
            float h  = (e2 - 1.f) / (e2 + 1.f);
            hv4[i] = h;
            _Float16 hf = (_Float16)h;
            __hip_atomic_store((short*)&hb[((size_t)par_w * NB + r) * HF + j],
                               __builtin_bit_cast(short, hf),
                               __ATOMIC_RELAXED, __HIP_MEMORY_SCOPE_AGENT);
        }

        // drain h stores, sync all 8 waves, publish
        asm volatile("s_waitcnt vmcnt(0)" ::: "memory");
        __syncthreads();
        if (tid == 0) {
            __hip_atomic_store(&grp_flags[wgidx], (unsigned int)(t + 1),
                               __ATOMIC_RELAXED, __HIP_MEMORY_SCOPE_AGENT);
        }

        // --- off-critical-path: out stores + ux prefetch for t+1 ---
        #pragma unroll
        for (int i = 0; i < 4; ++i) {
            int r = b0 + fkq * 4 + i;
            out[((size_t)r * SEQ + t) * HF + j] = hv4[i];
            if (t == SEQ - 1)
                out[(size_t)NB * SEQ * HF + (size_t)r * HF + j] = hv4[i];
        }
        if (t + 1 < SEQ) {
            #pragma unroll
            for (int i = 0; i < 4; ++i) {
                int r = b0 + fkq * 4 + i;
                ux[i] = out[((size_t)r * SEQ + (t + 1)) * HF + j];
            }
        }
    }
}

extern "C" void kernel_launch(void* const* d_in, const int* in_sizes, int n_in,
                              void* d_out, int out_size, void* d_ws, size_t ws_size,
                              hipStream_t stream) {
    const float* X  = (const float*)d_in[0];   // input_emb [64,512,1024]
    const float* Ww = (const float*)d_in[1];   // W_w [1024,1024]
    const float* Wb = (const float*)d_in[2];   // W_b [1024]
    const float* Uw = (const float*)d_in[3];   // U_w [1024,1024]
    const float* Ub = (const float*)d_in[4];   // U_b [1024]
    float* out = (float*)d_out;

    unsigned int* flags = (unsigned int*)d_ws;              // 4 groups x 16 u32
    _Float16* hb = (_Float16*)((char*)d_ws + 8192);         // 2*64*1024 f16 = 256 KB

    hipMemsetAsync(d_ws, 0, 8192, stream);
    ux_gemm<<<dim3(2048), dim3(256), 0, stream>>>(X, Uw, Ub, out);
    rnn_scan<<<dim3(32), dim3(512), 0, stream>>>(Ww, Wb, out, hb, flags);
}

// Round 6
// 2184.383 us; speedup vs baseline: 3.8974x; 3.8974x over previous
//
#include <hip/hip_runtime.h>
#include <hip/hip_bf16.h>

#define SEQ 512
#define NB  64
#define HF  1024

typedef float f32x4 __attribute__((ext_vector_type(4)));
typedef short s16x8 __attribute__((ext_vector_type(8)));
typedef short s16x4 __attribute__((ext_vector_type(4)));
typedef _Float16 f16x8 __attribute__((ext_vector_type(8)));

__device__ __forceinline__ unsigned short bf16_rne(float f) {
    unsigned u = __builtin_bit_cast(unsigned, f);
    u += 0x7FFFu + ((u >> 16) & 1u);
    return (unsigned short)(u >> 16);
}

// split f = hi + lo (hi = truncated bf16, lo = rne bf16 of exact remainder)
__device__ __forceinline__ void bf16_split(float f, short& hi, short& lo) {
    unsigned u = __builtin_bit_cast(unsigned, f);
    hi = (short)(u >> 16);
    float fh = __builtin_bit_cast(float, u & 0xFFFF0000u);
    lo = (short)bf16_rne(f - fh);
}

__device__ __forceinline__ f32x4 mfma16(s16x8 a, s16x8 b, f32x4 c) {
    return __builtin_amdgcn_mfma_f32_16x16x32_bf16(a, b, c, 0, 0, 0);
}

// ---------------------------------------------------------------------------
// Phase 1: Ux = X @ U^T + U_b   (written into d_out, layout [B,S,H] = [32768,1024])
// 128x128 tiles, K-step 32, split-bf16 (3-term) MFMA.  (unchanged — passed R2-R5)
// ---------------------------------------------------------------------------
__global__ __launch_bounds__(256, 2) void ux_gemm(const float* __restrict__ X,
                                                  const float* __restrict__ U,
                                                  const float* __restrict__ Ubias,
                                                  float* __restrict__ out) {
    __shared__ short Ah[128][40], Al[128][40], Bh[128][40], Bl[128][40];

    int bid = blockIdx.x;                    // 2048 = 256 m-tiles * 8 n-tiles
    int swz = (bid & 7) * 256 + (bid >> 3);  // XCD-contiguous chunks (2048 % 8 == 0)
    int tm = swz & 255;
    int tn = swz >> 8;

    int tid  = threadIdx.x;
    int lrow = tid >> 3;           // 0..31
    int lcol = (tid & 7) << 2;     // 0,4,..,28

    int wave = tid >> 6, lane = tid & 63;
    int wr = (wave >> 1) << 6;     // wave row offset (0/64)
    int wc = (wave & 1) << 6;      // wave col offset (0/64)
    int fr = lane & 15, fkq = lane >> 4;

    const float* Xb = X + (size_t)tm * 128 * HF;
    const float* Ub = U + (size_t)tn * 128 * HF;

    f32x4 acc[4][4];
    #pragma unroll
    for (int mi = 0; mi < 4; ++mi)
        #pragma unroll
        for (int ni = 0; ni < 4; ++ni)
            acc[mi][ni] = f32x4{0.f, 0.f, 0.f, 0.f};

    for (int kt = 0; kt < HF; kt += 32) {
        __syncthreads();
        #pragma unroll
        for (int p = 0; p < 4; ++p) {
            int r = lrow + (p << 5);
            f32x4 xv = *(const f32x4*)(Xb + (size_t)r * HF + kt + lcol);
            f32x4 uv = *(const f32x4*)(Ub + (size_t)r * HF + kt + lcol);
            s16x4 xh, xl, uh, ul;
            #pragma unroll
            for (int e = 0; e < 4; ++e) {
                short h_, l_;
                bf16_split(xv[e], h_, l_); xh[e] = h_; xl[e] = l_;
                bf16_split(uv[e], h_, l_); uh[e] = h_; ul[e] = l_;
            }
            *(s16x4*)&Ah[r][lcol] = xh;
            *(s16x4*)&Al[r][lcol] = xl;
            *(s16x4*)&Bh[r][lcol] = uh;
            *(s16x4*)&Bl[r][lcol] = ul;
        }
        __syncthreads();

        s16x8 afh[4], afl[4], bfh[4], bfl[4];
        #pragma unroll
        for (int mi = 0; mi < 4; ++mi) {
            afh[mi] = *(const s16x8*)&Ah[wr + mi * 16 + fr][fkq * 8];
            afl[mi] = *(const s16x8*)&Al[wr + mi * 16 + fr][fkq * 8];
            bfh[mi] = *(const s16x8*)&Bh[wc + mi * 16 + fr][fkq * 8];
            bfl[mi] = *(const s16x8*)&Bl[wc + mi * 16 + fr][fkq * 8];
        }
        #pragma unroll
        for (int mi = 0; mi < 4; ++mi)
            #pragma unroll
            for (int ni = 0; ni < 4; ++ni)
                acc[mi][ni] = mfma16(afh[mi], bfh[ni], acc[mi][ni]);
        #pragma unroll
        for (int mi = 0; mi < 4; ++mi)
            #pragma unroll
            for (int ni = 0; ni < 4; ++ni)
                acc[mi][ni] = mfma16(afh[mi], bfl[ni], acc[mi][ni]);
        #pragma unroll
        for (int mi = 0; mi < 4; ++mi)
            #pragma unroll
            for (int ni = 0; ni < 4; ++ni)
                acc[mi][ni] = mfma16(afl[mi], bfh[ni], acc[mi][ni]);
    }

    // epilogue: C/D layout col = lane&15, row = (lane>>4)*4 + i  [m89]
    #pragma unroll
    for (int ni = 0; ni < 4; ++ni) {
        int col = tn * 128 + wc + ni * 16 + fr;
        float ub = Ubias[col];
        #pragma unroll
        for (int mi = 0; mi < 4; ++mi) {
            #pragma unroll
            for (int i = 0; i < 4; ++i) {
                int row = tm * 128 + wr + mi * 16 + fkq * 4 + i;
                out[(size_t)row * HF + col] = acc[mi][ni][i] + ub;
            }
        }
    }
}

// ---------------------------------------------------------------------------
// Phase 2 v6: wave-autonomous, asm-batched LLC loads.
// 256 WGs x 64 thr: 4 groups x 64 waves; wave owns 16 cols, W f16 in AGPRs.
//   - 32 global_load_dwordx4 sc1 issued back-to-back (inline asm), counted
//     vmcnt(24/16/8/0) batch waits, asm MFMA (ordered vs waits).
//   - per-WAVE flags: drain own 4 h-stores (vmcnt 0) -> store own flag;
//     consumers poll 64 flags (lane i polls flag i), no __syncthreads at all.
//   - out stores + next ux prefetch after flag publish (off critical path).
// ---------------------------------------------------------------------------
#define LDF(dst, OFF) \
    asm volatile("global_load_dwordx4 %0, %1, off offset:" OFF " sc1" \
                 : "=v"(dst) : "v"(lanep) : "memory")
#define WAITV(N) asm volatile("s_waitcnt vmcnt(" N ")" ::: "memory")
#define MF(acc, hv, wv) \
    asm volatile("v_mfma_f32_16x16x32_f16 %0, %1, %2, %0" \
                 : "+v"(acc) : "v"(hv), "a"(wv))
#define MFMA8(Fb, K0) \
    MF(a0, Fb[0], wf[K0 + 0]); MF(a1, Fb[1], wf[K0 + 1]); \
    MF(a2, Fb[2], wf[K0 + 2]); MF(a3, Fb[3], wf[K0 + 3]); \
    MF(a0, Fb[4], wf[K0 + 4]); MF(a1, Fb[5], wf[K0 + 5]); \
    MF(a2, Fb[6], wf[K0 + 6]); MF(a3, Fb[7], wf[K0 + 7])

__global__ __launch_bounds__(64, 1) void rnn_scan(const float* __restrict__ Ww,
                                                  const float* __restrict__ Wb,
                                                  float* __restrict__ out,
                                                  _Float16* __restrict__ hb,
                                                  unsigned int* __restrict__ flags) {
    int bid   = blockIdx.x;        // 256 = 4 groups x 64 waves
    int btile = bid >> 6;          // 0..3  (16 batches each)
    int widx  = bid & 63;          // wave slot in group (owns cols widx*16..+15)
    int lane  = threadIdx.x;       // 0..63
    int fr    = lane & 15, fkq = lane >> 4;
    int j     = (widx << 4) + fr;  // this lane's output column
    int b0    = btile << 4;

    // --- prologue: W row j as f16 frags, pinned into AGPRs (128 regs) ---
    f16x8 wf[32];
    {
        const float* wp = Ww + (size_t)j * HF + fkq * 8;
        #pragma unroll
        for (int kt = 0; kt < 32; ++kt) {
            f32x4 a = *(const f32x4*)(wp + kt * 32);
            f32x4 b = *(const f32x4*)(wp + kt * 32 + 4);
            f16x8 w;
            #pragma unroll
            for (int e = 0; e < 4; ++e) {
                w[e]     = (_Float16)a[e];
                w[e + 4] = (_Float16)b[e];
            }
            wf[kt] = w;
        }
        #pragma unroll
        for (int kt = 0; kt < 32; ++kt)
            asm volatile("" : "+a"(wf[kt]));   // force AGPR residency
    }
    float wb = Wb[j];

    unsigned int* gf = flags + btile * 64;   // 64 per-wave flags for this group

    // ux for t=0
    float ux[4];
    #pragma unroll
    for (int i = 0; i < 4; ++i) {
        int r = b0 + fkq * 4 + i;
        ux[i] = out[((size_t)r * SEQ + 0) * HF + j];
    }

    #pragma unroll 1
    for (int t = 0; t < SEQ; ++t) {
        f32x4 sum = {0.f, 0.f, 0.f, 0.f};
        if (t > 0) {
            // poll: lane i watches wave i's flag; exit when all 64 >= t
            unsigned int v;
            do {
                v = __hip_atomic_load(&gf[lane], __ATOMIC_RELAXED,
                                      __HIP_MEMORY_SCOPE_AGENT);
            } while (!__all(v >= (unsigned int)t));

            // lane (fr,fkq) fragment base: hb[b0+fr][fkq*8], kt stride 64B
            int par = (t - 1) & 1;
            const _Float16* lanep =
                hb + ((size_t)par * NB + b0 + fr) * HF + fkq * 8;

            f16x8 F0[8], F1[8], F2[8], F3[8];
            LDF(F0[0], "0");    LDF(F0[1], "64");   LDF(F0[2], "128");  LDF(F0[3], "192");
            LDF(F0[4], "256");  LDF(F0[5], "320");  LDF(F0[6], "384");  LDF(F0[7], "448");
            LDF(F1[0], "512");  LDF(F1[1], "576");  LDF(F1[2], "640");  LDF(F1[3], "704");
            LDF(F1[4], "768");  LDF(F1[5], "832");  LDF(F1[6], "896");  LDF(F1[7], "960");
            LDF(F2[0], "1024"); LDF(F2[1], "1088"); LDF(F2[2], "1152"); LDF(F2[3], "1216");
            LDF(F2[4], "1280"); LDF(F2[5], "1344"); LDF(F2[6], "1408"); LDF(F2[7], "1472");
            LDF(F3[0], "1536"); LDF(F3[1], "1600"); LDF(F3[2], "1664"); LDF(F3[3], "1728");
            LDF(F3[4], "1792"); LDF(F3[5], "1856"); LDF(F3[6], "1920"); LDF(F3[7], "1984");

            f32x4 a0 = {0.f,0.f,0.f,0.f}, a1 = a0, a2 = a0, a3 = a0;
            WAITV("24");  MFMA8(F0, 0);
            WAITV("16");  MFMA8(F1, 8);
            WAITV("8");   MFMA8(F2, 16);
            WAITV("0");   MFMA8(F3, 24);
            sum = (a0 + a1) + (a2 + a3);
        }

        // --- compute h; store ONLY h (sc1 -> LLC) before the flag ---
        float hv4[4];
        int par_w = t & 1;
        #pragma unroll
        for (int i = 0; i < 4; ++i) {
            int r = b0 + fkq * 4 + i;
            float p = ux[i] + sum[i] + wb;
            p = fminf(fmaxf(p, -12.f), 12.f);
            float e2 = __expf(2.f * p);
            float h  = (e2 - 1.f) / (e2 + 1.f);
            hv4[i] = h;
            _Float16 hf = (_Float16)h;
            __hip_atomic_store((short*)&hb[((size_t)par_w * NB + r) * HF + j],
                               __builtin_bit_cast(short, hf),
                               __ATOMIC_RELAXED, __HIP_MEMORY_SCOPE_AGENT);
        }

        // drain own h stores, publish own flag (per-wave; no barrier)
        WAITV("0");
        __hip_atomic_store(&gf[widx], (unsigned int)(t + 1),
                           __ATOMIC_RELAXED, __HIP_MEMORY_SCOPE_AGENT);

        // --- off-critical-path: out stores + ux prefetch for t+1 ---
        #pragma unroll
        for (int i = 0; i < 4; ++i) {
            int r = b0 + fkq * 4 + i;
            out[((size_t)r * SEQ + t) * HF + j] = hv4[i];
            if (t == SEQ - 1)
                out[(size_t)NB * SEQ * HF + (size_t)r * HF + j] = hv4[i];
        }
        if (t + 1 < SEQ) {
            #pragma unroll
            for (int i = 0; i < 4; ++i) {
                int r = b0 + fkq * 4 + i;
                ux[i] = out[((size_t)r * SEQ + (t + 1)) * HF + j];
            }
        }
    }
}

extern "C" void kernel_launch(void* const* d_in, const int* in_sizes, int n_in,
                              void* d_out, int out_size, void* d_ws, size_t ws_size,
                              hipStream_t stream) {
    const float* X  = (const float*)d_in[0];   // input_emb [64,512,1024]
    const float* Ww = (const float*)d_in[1];   // W_w [1024,1024]
    const float* Wb = (const float*)d_in[2];   // W_b [1024]
    const float* Uw = (const float*)d_in[3];   // U_w [1024,1024]
    const float* Ub = (const float*)d_in[4];   // U_b [1024]
    float* out = (float*)d_out;

    unsigned int* flags = (unsigned int*)d_ws;              // 4 groups x 64 u32
    _Float16* hb = (_Float16*)((char*)d_ws + 8192);         // 2*64*1024 f16 = 256 KB

    hipMemsetAsync(d_ws, 0, 8192, stream);
    ux_gemm<<<dim3(2048), dim3(256), 0, stream>>>(X, Uw, Ub, out);
    rnn_scan<<<dim3(256), dim3(64), 0, stream>>>(Ww, Wb, out, hb, flags);
}